// Round 3
// baseline (249.578 us; speedup 1.0000x reference)
//
#include <hip/hip_runtime.h>
#include <hip/hip_bf16.h>
#include <stdint.h>

typedef __hip_bfloat16 bf16;
typedef __attribute__((ext_vector_type(8))) short short8;
typedef __attribute__((ext_vector_type(4))) float floatx4;

#define DEVI static __device__ __forceinline__

typedef __attribute__((address_space(1))) const uint32_t gu32;
typedef __attribute__((address_space(3))) uint32_t lu32;

DEVI void gld_lds16(const void* g, void* l) {
    __builtin_amdgcn_global_load_lds((gu32*)g, (lu32*)l, 16, 0, 0);
}

DEVI bf16 us2bf(unsigned short s) { union { unsigned short u; bf16 h; } t; t.u = s; return t.h; }

// RoPE work item count: b(2) * n1(2047) * {q,k}(2) * h(16) * j(32)
#define ROPE_N (2 * 2047 * 2 * 16 * 32)   // = 4,192,256 -> 16,376 blocks of 256

// ---------------- fp32 -> bf16 convert ----------------
__global__ void cvt_bf16_kernel(const float* __restrict__ src, bf16* __restrict__ dst, int n) {
    int i = (blockIdx.x * 256 + threadIdx.x) * 4;
    if (i >= n) return;
    float4 v = *(const float4*)(src + i);
    union { bf16 h[4]; uint2 u; } o;
    o.h[0] = __float2bfloat16(v.x);
    o.h[1] = __float2bfloat16(v.y);
    o.h[2] = __float2bfloat16(v.z);
    o.h[3] = __float2bfloat16(v.w);
    *(uint2*)(dst + i) = o.u;
}

// ---------------- m97-style bf16 GEMM:  C[M][N] = A[M][K] * Bt[N][K]^T ----------------
// 128x128 tile, BK=32, 4 waves in 2x2, each wave 64x64 (4x4 frags of 16x16x32)
template<int OUT_BF16, int ADD_BIAS>
__global__ __launch_bounds__(256, 2) void gemm_bt_kernel(
    const bf16* __restrict__ A, const bf16* __restrict__ Bt,
    const float* __restrict__ bias, void* __restrict__ Cout,
    int M, int N, int K, int nbn)
{
    constexpr int BK = 32;
    __shared__ __align__(16) bf16 As[128 * BK];
    __shared__ __align__(16) bf16 Bs[128 * BK];
    const int bm = blockIdx.x / nbn;
    const int bn = blockIdx.x % nbn;
    const int lane = threadIdx.x & 63;
    const int wave = threadIdx.x >> 6;
    const int wm = (wave >> 1) << 6;
    const int wn = (wave & 1) << 6;

    // staging: 8 chunks of 1024B per operand tile; wave w owns chunks w and w+4
    // chunk c covers rows [c*16, c*16+16): lane l -> row c*16 + l/4, col (l&3)*8
    const int srow0 = wave * 16 + (lane >> 2);
    const int srow1 = srow0 + 64;
    const int skc = (lane & 3) * 8;
    const bf16* Ap0 = A + (size_t)(bm * 128 + srow0) * K + skc;
    const bf16* Ap1 = A + (size_t)(bm * 128 + srow1) * K + skc;
    const bf16* Bp0 = Bt + (size_t)(bn * 128 + srow0) * K + skc;
    const bf16* Bp1 = Bt + (size_t)(bn * 128 + srow1) * K + skc;
    bf16* As0 = &As[wave * 512];
    bf16* As1 = &As[wave * 512 + 2048];
    bf16* Bs0 = &Bs[wave * 512];
    bf16* Bs1 = &Bs[wave * 512 + 2048];

    const int frow = lane & 15;          // A/B frag: non-K index = lane&15
    const int fk   = (lane >> 4) * 8;    // K-group of 8, contiguous

    floatx4 acc[4][4] = {};

    for (int kt = 0; kt < K; kt += BK) {
        gld_lds16(Ap0 + kt, As0);
        gld_lds16(Ap1 + kt, As1);
        gld_lds16(Bp0 + kt, Bs0);
        gld_lds16(Bp1 + kt, Bs1);
        __syncthreads();   // drains vmcnt(0) -> staged data visible
        short8 af[4], bfv[4];
#pragma unroll
        for (int m = 0; m < 4; ++m) af[m] = *(const short8*)&As[(wm + m * 16 + frow) * BK + fk];
#pragma unroll
        for (int n = 0; n < 4; ++n) bfv[n] = *(const short8*)&Bs[(wn + n * 16 + frow) * BK + fk];
#pragma unroll
        for (int m = 0; m < 4; ++m)
#pragma unroll
            for (int n = 0; n < 4; ++n)
                acc[m][n] = __builtin_amdgcn_mfma_f32_16x16x32_bf16(af[m], bfv[n], acc[m][n], 0, 0, 0);
        __syncthreads();   // all waves done reading before next stage overwrites
    }

    // C/D layout: col = lane&15, row = (lane>>4)*4 + reg   [m89-verified]
    const int rbase = bm * 128 + wm + (lane >> 4) * 4;
    const int cbase = bn * 128 + wn + (lane & 15);
#pragma unroll
    for (int m = 0; m < 4; ++m)
#pragma unroll
        for (int n = 0; n < 4; ++n) {
            const int col = cbase + n * 16;
            float bv = ADD_BIAS ? bias[col] : 0.f;
#pragma unroll
            for (int r = 0; r < 4; ++r) {
                const size_t idx = (size_t)(rbase + m * 16 + r) * N + col;
                float v = acc[m][n][r] + bv;
                if (OUT_BF16) ((bf16*)Cout)[idx] = __float2bfloat16(v);
                else          ((float*)Cout)[idx] = v;
            }
        }
}

// ---------------- RoPE in-place on q,k slices of qkv [4096][3072] ----------------
// prefix = 1: token n=0 unrotated; token n>=1 uses sin/cos row n-1.
__global__ void rope_kernel(bf16* __restrict__ qkv, const float* __restrict__ sinp,
                            const float* __restrict__ cosp) {
    int idx = blockIdx.x * 256 + threadIdx.x;
    if (idx >= ROPE_N) return;
    const int j = idx & 31;
    int t = idx >> 5;
    const int h = t & 15; t >>= 4;
    const int w = t & 1;  t >>= 1;
    const int n1 = t % 2047;
    const int b  = t / 2047;
    const size_t off = (size_t)(b * 2048 + n1 + 1) * 3072 + w * 1024 + h * 64 + j;
    const float x1 = __bfloat162float(qkv[off]);
    const float x2 = __bfloat162float(qkv[off + 32]);
    const int sc = n1 * 64 + j;
    const float c1 = cosp[sc], s1 = sinp[sc];
    const float c2 = cosp[sc + 32], s2 = sinp[sc + 32];
    qkv[off]      = __float2bfloat16(x1 * c1 - x2 * s1);   // x*cos + (-x2)*sin
    qkv[off + 32] = __float2bfloat16(x2 * c2 + x1 * s2);   // x2*cos + x1*sin
}

// ---------------- flash attention: 4 waves/block, wave = 16 q-rows, KBLK=64 ----------------
__global__ __launch_bounds__(256, 2) void attn_kernel(const bf16* __restrict__ qkv,
                                                      bf16* __restrict__ O) {
    constexpr int LDK = 72;   // padded leading dim (144B rows) -> ~2-way max on b128
    __shared__ __align__(16) bf16 Ks[64 * LDK];      // [k][d]
    __shared__ __align__(16) bf16 Vt[64 * LDK];      // [d][k]
    __shared__ __align__(16) bf16 Pl[4][16 * LDK];   // per-wave [q][k]

    const int bh = blockIdx.x >> 5;
    const int qt = blockIdx.x & 31;
    const int b = bh >> 4;
    const int h = bh & 15;
    const int lane = threadIdx.x & 63;
    const int wave = threadIdx.x >> 6;
    const int t = threadIdx.x;

    const bf16* qb = qkv + (size_t)b * 2048 * 3072 + h * 64;
    const bf16* kb = qb + 1024;
    const bf16* vb = qb + 2048;

    const int frow = lane & 15;
    const int fk   = (lane >> 4) * 8;
    const int q0   = qt * 64 + wave * 16;

    // Q strip [16][64] in regs: A-frags for the 2 K-groups of the d-contraction
    short8 qf0 = *(const short8*)(qb + (size_t)(q0 + frow) * 3072 + fk);
    short8 qf1 = *(const short8*)(qb + (size_t)(q0 + frow) * 3072 + 32 + fk);

    floatx4 acc[4] = {};                       // [d-tile][row-reg]
    float mrow[4] = {-1e30f, -1e30f, -1e30f, -1e30f};
    float lrow[4] = {0.f, 0.f, 0.f, 0.f};

    // staging map: 512 chunks of 8 bf16; thread does chunks t and t+256
    const int sr0 = t >> 3;           // k-row 0..31
    const int sr1 = sr0 + 32;
    const int sdc = (t & 7) * 8;      // d-offset

    for (int k0 = 0; k0 < 2048; k0 += 64) {
        __syncthreads();  // previous tile's LDS reads complete
        short8 kv0 = *(const short8*)(kb + (size_t)(k0 + sr0) * 3072 + sdc);
        short8 kv1 = *(const short8*)(kb + (size_t)(k0 + sr1) * 3072 + sdc);
        short8 vv0 = *(const short8*)(vb + (size_t)(k0 + sr0) * 3072 + sdc);
        short8 vv1 = *(const short8*)(vb + (size_t)(k0 + sr1) * 3072 + sdc);
        *(short8*)&Ks[sr0 * LDK + sdc] = kv0;
        *(short8*)&Ks[sr1 * LDK + sdc] = kv1;
#pragma unroll
        for (int j = 0; j < 8; ++j) {
            Vt[(sdc + j) * LDK + sr0] = us2bf((unsigned short)vv0[j]);
            Vt[(sdc + j) * LDK + sr1] = us2bf((unsigned short)vv1[j]);
        }
        __syncthreads();  // staging visible

        // S = Q*K^T * scale : 4 k-tiles of 16x16
        floatx4 s[4];
#pragma unroll
        for (int kt = 0; kt < 4; ++kt) {
            const bf16* kr = &Ks[(kt * 16 + frow) * LDK + fk];
            floatx4 z = {};
            z = __builtin_amdgcn_mfma_f32_16x16x32_bf16(qf0, *(const short8*)kr, z, 0, 0, 0);
            z = __builtin_amdgcn_mfma_f32_16x16x32_bf16(qf1, *(const short8*)(kr + 32), z, 0, 0, 0);
            s[kt] = z;
        }
#pragma unroll
        for (int kt = 0; kt < 4; ++kt)
#pragma unroll
            for (int r = 0; r < 4; ++r) s[kt][r] *= 0.125f;

        // online softmax per row; 16 lanes (bits 0..3) share a row
#pragma unroll
        for (int r = 0; r < 4; ++r) {
            float mx = fmaxf(fmaxf(s[0][r], s[1][r]), fmaxf(s[2][r], s[3][r]));
            mx = fmaxf(mx, __shfl_xor(mx, 1));
            mx = fmaxf(mx, __shfl_xor(mx, 2));
            mx = fmaxf(mx, __shfl_xor(mx, 4));
            mx = fmaxf(mx, __shfl_xor(mx, 8));
            const float mnew = fmaxf(mrow[r], mx);
            const float corr = __expf(mrow[r] - mnew);
            mrow[r] = mnew;
            const bf16 b0 = __float2bfloat16(__expf(s[0][r] - mnew));
            const bf16 b1 = __float2bfloat16(__expf(s[1][r] - mnew));
            const bf16 b2 = __float2bfloat16(__expf(s[2][r] - mnew));
            const bf16 b3 = __float2bfloat16(__expf(s[3][r] - mnew));
            // denominator from the SAME rounded values PV will consume
            float rs = __bfloat162float(b0) + __bfloat162float(b1)
                     + __bfloat162float(b2) + __bfloat162float(b3);
            rs += __shfl_xor(rs, 1);
            rs += __shfl_xor(rs, 2);
            rs += __shfl_xor(rs, 4);
            rs += __shfl_xor(rs, 8);
            lrow[r] = lrow[r] * corr + rs;
#pragma unroll
            for (int dt = 0; dt < 4; ++dt) acc[dt][r] *= corr;
            const int prow = ((lane >> 4) * 4 + r) * LDK + (lane & 15);
            Pl[wave][prow]      = b0;
            Pl[wave][prow + 16] = b1;
            Pl[wave][prow + 32] = b2;
            Pl[wave][prow + 48] = b3;
        }

        // Barrier between scattered scalar P-writes and the vector fragment reads
        // below (compiler fence + HW ordering; all waves reach this uniformly).
        __syncthreads();

        // PV: A = P [16 q][64 k], B = V^T from Vt
        short8 pa0 = *(const short8*)&Pl[wave][frow * LDK + fk];
        short8 pa1 = *(const short8*)&Pl[wave][frow * LDK + 32 + fk];
#pragma unroll
        for (int dt = 0; dt < 4; ++dt) {
            const bf16* vr = &Vt[(dt * 16 + frow) * LDK + fk];
            acc[dt] = __builtin_amdgcn_mfma_f32_16x16x32_bf16(pa0, *(const short8*)vr, acc[dt], 0, 0, 0);
            acc[dt] = __builtin_amdgcn_mfma_f32_16x16x32_bf16(pa1, *(const short8*)(vr + 32), acc[dt], 0, 0, 0);
        }
    }

    const int nrow = q0 + (lane >> 4) * 4;
#pragma unroll
    for (int r = 0; r < 4; ++r) {
        const float inv = 1.0f / lrow[r];
        const size_t base = ((size_t)b * 2048 + nrow + r) * 1024 + h * 64 + (lane & 15);
#pragma unroll
        for (int dt = 0; dt < 4; ++dt)
            O[base + dt * 16] = __float2bfloat16(acc[dt][r] * inv);
    }
}

extern "C" void kernel_launch(void* const* d_in, const int* in_sizes, int n_in,
                              void* d_out, int out_size, void* d_ws, size_t ws_size,
                              hipStream_t stream) {
    const float* x      = (const float*)d_in[0];   // [2,2048,1024]
    const float* sinp   = (const float*)d_in[1];   // [2047,64]
    const float* cosp   = (const float*)d_in[2];   // [2047,64]
    const float* qkv_w  = (const float*)d_in[3];   // [3072,1024]
    const float* proj_w = (const float*)d_in[4];   // [1024,1024]
    const float* proj_b = (const float*)d_in[5];   // [1024]
    float* out = (float*)d_out;

    char* ws = (char*)d_ws;
    bf16* xb    = (bf16*)(ws);                          //  8,388,608 B
    bf16* wqkv  = (bf16*)(ws + 8388608);                //  6,291,456 B
    bf16* wproj = (bf16*)(ws + 8388608 + 6291456);      //  2,097,152 B
    bf16* qkvb  = (bf16*)(ws + 16777216);               // 25,165,824 B  [4096][3072]
    bf16* attno = (bf16*)(ws + 16777216 + 25165824);    //  8,388,608 B  [4096][1024]

    cvt_bf16_kernel<<<4096, 256, 0, stream>>>(x, xb, 4194304);
    cvt_bf16_kernel<<<3072, 256, 0, stream>>>(qkv_w, wqkv, 3145728);
    cvt_bf16_kernel<<<1024, 256, 0, stream>>>(proj_w, wproj, 1048576);

    // qkv = x @ qkv_w^T  : M=4096 N=3072 K=1024
    gemm_bt_kernel<1, 0><<<32 * 24, 256, 0, stream>>>(xb, wqkv, nullptr, qkvb,
                                                      4096, 3072, 1024, 24);
    // RoPE on q,k (rows n>=1): exact block count for 4,192,256 work items
    rope_kernel<<<(ROPE_N + 255) / 256, 256, 0, stream>>>(qkvb, sinp, cosp);
    // attention -> attno [4096][1024]
    attn_kernel<<<1024, 256, 0, stream>>>(qkvb, attno);
    // out = attno @ proj_w^T + proj_b : M=4096 N=1024 K=1024
    gemm_bt_kernel<0, 1><<<32 * 8, 256, 0, stream>>>(attno, wproj, proj_b, out,
                                                     4096, 1024, 1024, 8);
}

// Round 4
// 204.620 us; speedup vs baseline: 1.2197x; 1.2197x over previous
//
#include <hip/hip_runtime.h>
#include <hip/hip_bf16.h>
#include <stdint.h>

typedef __hip_bfloat16 bf16;
typedef __attribute__((ext_vector_type(8))) short short8;
typedef __attribute__((ext_vector_type(4))) float floatx4;

#define DEVI static __device__ __forceinline__

typedef __attribute__((address_space(1))) const uint32_t gu32;
typedef __attribute__((address_space(3))) uint32_t lu32;

DEVI void gld_lds16(const void* g, void* l) {
    __builtin_amdgcn_global_load_lds((gu32*)g, (lu32*)l, 16, 0, 0);
}

DEVI unsigned short bf2us(bf16 h) { union { bf16 h; unsigned short u; } t; t.h = h; return t.u; }

// RoPE work item count: b(2) * n1(2047) * {q,k}(2) * h(16) * j(32)
#define ROPE_N (2 * 2047 * 2 * 16 * 32)

// ---------------- fp32 -> bf16 convert ----------------
__global__ void cvt_bf16_kernel(const float* __restrict__ src, bf16* __restrict__ dst, int n) {
    int i = (blockIdx.x * 256 + threadIdx.x) * 4;
    if (i >= n) return;
    float4 v = *(const float4*)(src + i);
    union { bf16 h[4]; uint2 u; } o;
    o.h[0] = __float2bfloat16(v.x);
    o.h[1] = __float2bfloat16(v.y);
    o.h[2] = __float2bfloat16(v.z);
    o.h[3] = __float2bfloat16(v.w);
    *(uint2*)(dst + i) = o.u;
}

// ---------------- m97-style bf16 GEMM:  C[M][N] = A[M][K] * Bt[N][K]^T ----------------
template<int OUT_BF16, int ADD_BIAS>
__global__ __launch_bounds__(256, 2) void gemm_bt_kernel(
    const bf16* __restrict__ A, const bf16* __restrict__ Bt,
    const float* __restrict__ bias, void* __restrict__ Cout,
    int M, int N, int K, int nbn)
{
    constexpr int BK = 32;
    __shared__ __align__(16) bf16 As[128 * BK];
    __shared__ __align__(16) bf16 Bs[128 * BK];
    const int bm = blockIdx.x / nbn;
    const int bn = blockIdx.x % nbn;
    const int lane = threadIdx.x & 63;
    const int wave = threadIdx.x >> 6;
    const int wm = (wave >> 1) << 6;
    const int wn = (wave & 1) << 6;

    const int srow0 = wave * 16 + (lane >> 2);
    const int srow1 = srow0 + 64;
    const int skc = (lane & 3) * 8;
    const bf16* Ap0 = A + (size_t)(bm * 128 + srow0) * K + skc;
    const bf16* Ap1 = A + (size_t)(bm * 128 + srow1) * K + skc;
    const bf16* Bp0 = Bt + (size_t)(bn * 128 + srow0) * K + skc;
    const bf16* Bp1 = Bt + (size_t)(bn * 128 + srow1) * K + skc;
    bf16* As0 = &As[wave * 512];
    bf16* As1 = &As[wave * 512 + 2048];
    bf16* Bs0 = &Bs[wave * 512];
    bf16* Bs1 = &Bs[wave * 512 + 2048];

    const int frow = lane & 15;
    const int fk   = (lane >> 4) * 8;

    floatx4 acc[4][4] = {};

    for (int kt = 0; kt < K; kt += BK) {
        gld_lds16(Ap0 + kt, As0);
        gld_lds16(Ap1 + kt, As1);
        gld_lds16(Bp0 + kt, Bs0);
        gld_lds16(Bp1 + kt, Bs1);
        __syncthreads();
        short8 af[4], bfv[4];
#pragma unroll
        for (int m = 0; m < 4; ++m) af[m] = *(const short8*)&As[(wm + m * 16 + frow) * BK + fk];
#pragma unroll
        for (int n = 0; n < 4; ++n) bfv[n] = *(const short8*)&Bs[(wn + n * 16 + frow) * BK + fk];
#pragma unroll
        for (int m = 0; m < 4; ++m)
#pragma unroll
            for (int n = 0; n < 4; ++n)
                acc[m][n] = __builtin_amdgcn_mfma_f32_16x16x32_bf16(af[m], bfv[n], acc[m][n], 0, 0, 0);
        __syncthreads();
    }

    const int rbase = bm * 128 + wm + (lane >> 4) * 4;
    const int cbase = bn * 128 + wn + (lane & 15);
#pragma unroll
    for (int m = 0; m < 4; ++m)
#pragma unroll
        for (int n = 0; n < 4; ++n) {
            const int col = cbase + n * 16;
            float bv = ADD_BIAS ? bias[col] : 0.f;
#pragma unroll
            for (int r = 0; r < 4; ++r) {
                const size_t idx = (size_t)(rbase + m * 16 + r) * N + col;
                float v = acc[m][n][r] + bv;
                if (OUT_BF16) ((bf16*)Cout)[idx] = __float2bfloat16(v);
                else          ((float*)Cout)[idx] = v;
            }
        }
}

// ---------------- RoPE in-place on q,k slices of qkv [4096][3072] ----------------
__global__ void rope_kernel(bf16* __restrict__ qkv, const float* __restrict__ sinp,
                            const float* __restrict__ cosp) {
    int idx = blockIdx.x * 256 + threadIdx.x;
    if (idx >= ROPE_N) return;
    const int j = idx & 31;
    int t = idx >> 5;
    const int h = t & 15; t >>= 4;
    const int w = t & 1;  t >>= 1;
    const int n1 = t % 2047;
    const int b  = t / 2047;
    const size_t off = (size_t)(b * 2048 + n1 + 1) * 3072 + w * 1024 + h * 64 + j;
    const float x1 = __bfloat162float(qkv[off]);
    const float x2 = __bfloat162float(qkv[off + 32]);
    const int sc = n1 * 64 + j;
    const float c1 = cosp[sc], s1 = sinp[sc];
    const float c2 = cosp[sc + 32], s2 = sinp[sc + 32];
    qkv[off]      = __float2bfloat16(x1 * c1 - x2 * s1);
    qkv[off + 32] = __float2bfloat16(x2 * c2 + x1 * s2);
}

// ---------------- flash attention v2 ----------------
// 4 waves/block, wave = 32 q-rows (2 strips of 16), block = 128 q-rows, KVBLK=64.
// K in LDS [64][64] linear via global_load_lds with XOR-swizzled SOURCE (chunk^=row&7),
//   reads apply the same XOR -> bank-floor access.
// V transposed in LDS [d][k'] with k' = (k&15)*4 + (k>>4); staged as 4x4 blocks via
//   ds_write_b64. P written in the SAME k' order via ds_write_b64 (permutation cancels
//   in the PV contraction). Grid: bh = bid&31 (same (b,h) -> same XCD -> K/V L2-resident).
__global__ __launch_bounds__(256, 2) void attn_kernel(const bf16* __restrict__ qkv,
                                                      bf16* __restrict__ O) {
    constexpr int LDV = 72;   // Vt leading dim (144B rows)
    constexpr int LDP = 72;   // P leading dim
    __shared__ __align__(16) bf16 Ks[64 * 64];        // 8 KiB, swizzled chunks
    __shared__ __align__(16) bf16 Vt[64 * LDV];       // 9 KiB
    __shared__ __align__(16) bf16 Pl[4][2][16 * LDP]; // 18 KiB

    const int bid = blockIdx.x;
    const int bh = bid & 31;        // XCD-friendly: same (b,h) -> same XCD
    const int qt = bid >> 5;
    const int b = bh >> 4;
    const int h = bh & 15;
    const int lane = threadIdx.x & 63;
    const int wave = threadIdx.x >> 6;
    const int t = threadIdx.x;

    const bf16* qb = qkv + (size_t)b * 2048 * 3072 + h * 64;
    const bf16* kb = qb + 1024;
    const bf16* vb = qb + 2048;

    const int frow = lane & 15;     // fragment row (non-K index)
    const int ks   = lane >> 4;     // k-slice 0..3
    const int fk   = ks * 8;        // contraction offset (8 contiguous elems)
    const int q0   = qt * 128 + wave * 32;

    // Q strips in registers: 2 strips x 2 d-halves
    short8 qf[2][2];
#pragma unroll
    for (int s = 0; s < 2; ++s) {
        const bf16* qr = qb + (size_t)(q0 + s * 16 + frow) * 3072;
        qf[s][0] = *(const short8*)(qr + fk);
        qf[s][1] = *(const short8*)(qr + 32 + fk);
    }

    // K staging: wave handles stripes {wave, wave+4} (8 rows each).
    // lane -> row_in_stripe = lane>>3, physical chunk = lane&7,
    // source chunk = (lane&7) ^ (lane>>3)  [inverse swizzle at the source]
    const int krow0 = wave * 8 + (lane >> 3);
    const int kchunk = ((lane & 7) ^ (lane >> 3)) * 8;   // elems
    const bf16* Kp0 = kb + (size_t)krow0 * 3072 + kchunk;
    const bf16* Kp1 = kb + (size_t)(krow0 + 32) * 3072 + kchunk;
    bf16* KsDst0 = &Ks[wave * 512];
    bf16* KsDst1 = &Ks[(wave + 4) * 512];

    // V transpose map: ra = t>>4 (k-base 0..15), cb = t&15 (d-group)
    const int ra = t >> 4;
    const int cb = t & 15;

    floatx4 acc[2][4] = {};
    float mrow[2][4], lrow[2][4];
#pragma unroll
    for (int s = 0; s < 2; ++s)
#pragma unroll
        for (int r = 0; r < 4; ++r) { mrow[s][r] = -1e30f; lrow[s][r] = 0.f; }

    for (int k0 = 0; k0 < 2048; k0 += 64) {
        __syncthreads();   // (A) previous tile's LDS reads complete

        // ---- stage V: 4 rows (16 apart) x 4 cols per thread ----
        union { ushort4 v; unsigned short e[4]; } vv[4];
#pragma unroll
        for (int kt = 0; kt < 4; ++kt)
            vv[kt].v = *(const ushort4*)(vb + (size_t)(k0 + ra + kt * 16) * 3072 + cb * 4);
        // ---- stage K: direct-to-LDS, pre-swizzled source ----
        gld_lds16(Kp0 + (size_t)k0 * 3072, KsDst0);
        gld_lds16(Kp1 + (size_t)k0 * 3072, KsDst1);
        // ---- V transposed writes: b64 of 4 k' values at row d ----
#pragma unroll
        for (int j = 0; j < 4; ++j) {
            union { unsigned short u[4]; unsigned long long ll; } pk;
            pk.u[0] = vv[0].e[j]; pk.u[1] = vv[1].e[j];
            pk.u[2] = vv[2].e[j]; pk.u[3] = vv[3].e[j];
            *(unsigned long long*)&Vt[(cb * 4 + j) * LDV + ra * 4] = pk.ll;
        }
        __syncthreads();   // (B) staging visible (drains vmcnt+lgkm)

        // ---- K fragments (shared by both strips), swizzled read ----
        short8 kf0[4], kf1[4];
#pragma unroll
        for (int kt = 0; kt < 4; ++kt) {
            const int row = kt * 16 + frow;
            const int p1 = (ks ^ (row & 7)) * 8;
            const int p2 = ((ks + 4) ^ (row & 7)) * 8;
            kf0[kt] = *(const short8*)&Ks[row * 64 + p1];
            kf1[kt] = *(const short8*)&Ks[row * 64 + p2];
        }

        // ---- per strip: QK^T, online softmax, pack P ----
#pragma unroll
        for (int s = 0; s < 2; ++s) {
            floatx4 sv[4];
#pragma unroll
            for (int kt = 0; kt < 4; ++kt) {
                floatx4 z = {};
                z = __builtin_amdgcn_mfma_f32_16x16x32_bf16(qf[s][0], kf0[kt], z, 0, 0, 0);
                z = __builtin_amdgcn_mfma_f32_16x16x32_bf16(qf[s][1], kf1[kt], z, 0, 0, 0);
                sv[kt] = z;
            }
#pragma unroll
            for (int kt = 0; kt < 4; ++kt)
#pragma unroll
                for (int r = 0; r < 4; ++r) sv[kt][r] *= 0.125f;

#pragma unroll
            for (int r = 0; r < 4; ++r) {
                float mx = fmaxf(fmaxf(sv[0][r], sv[1][r]), fmaxf(sv[2][r], sv[3][r]));
                mx = fmaxf(mx, __shfl_xor(mx, 1));
                mx = fmaxf(mx, __shfl_xor(mx, 2));
                mx = fmaxf(mx, __shfl_xor(mx, 4));
                mx = fmaxf(mx, __shfl_xor(mx, 8));
                const float mnew = fmaxf(mrow[s][r], mx);
                const float corr = __expf(mrow[s][r] - mnew);
                mrow[s][r] = mnew;
                union { unsigned short u[4]; unsigned long long ll; } pk;
                float rs = 0.f;
#pragma unroll
                for (int kt = 0; kt < 4; ++kt) {
                    const bf16 pb = __float2bfloat16(__expf(sv[kt][r] - mnew));
                    pk.u[kt] = bf2us(pb);
                    rs += __bfloat162float(pb);   // denom from the rounded values PV uses
                }
                rs += __shfl_xor(rs, 1);
                rs += __shfl_xor(rs, 2);
                rs += __shfl_xor(rs, 4);
                rs += __shfl_xor(rs, 8);
                lrow[s][r] = lrow[s][r] * corr + rs;
#pragma unroll
                for (int dt = 0; dt < 4; ++dt) acc[s][dt][r] *= corr;
                // P row g*4+r, k' = c*4 + kt contiguous -> one b64
                *(unsigned long long*)&Pl[wave][s][(ks * 4 + r) * LDP + frow * 4] = pk.ll;
            }
        }
        __syncthreads();   // (C) P visible; also fences P write->read ordering

        // ---- V fragments (shared by both strips) ----
        short8 vf0[4], vf1[4];
#pragma unroll
        for (int dt = 0; dt < 4; ++dt) {
            const int d = dt * 16 + frow;
            vf0[dt] = *(const short8*)&Vt[d * LDV + fk];
            vf1[dt] = *(const short8*)&Vt[d * LDV + 32 + fk];
        }
        // ---- PV per strip ----
#pragma unroll
        for (int s = 0; s < 2; ++s) {
            const short8 pa0 = *(const short8*)&Pl[wave][s][frow * LDP + fk];
            const short8 pa1 = *(const short8*)&Pl[wave][s][frow * LDP + 32 + fk];
#pragma unroll
            for (int dt = 0; dt < 4; ++dt) {
                acc[s][dt] = __builtin_amdgcn_mfma_f32_16x16x32_bf16(pa0, vf0[dt], acc[s][dt], 0, 0, 0);
                acc[s][dt] = __builtin_amdgcn_mfma_f32_16x16x32_bf16(pa1, vf1[dt], acc[s][dt], 0, 0, 0);
            }
        }
    }

    // epilogue
#pragma unroll
    for (int s = 0; s < 2; ++s) {
        const int nrow = q0 + s * 16 + ks * 4;
#pragma unroll
        for (int r = 0; r < 4; ++r) {
            const float inv = 1.0f / lrow[s][r];
            const size_t base = ((size_t)b * 2048 + nrow + r) * 1024 + h * 64 + frow;
#pragma unroll
            for (int dt = 0; dt < 4; ++dt)
                O[base + dt * 16] = __float2bfloat16(acc[s][dt][r] * inv);
        }
    }
}

extern "C" void kernel_launch(void* const* d_in, const int* in_sizes, int n_in,
                              void* d_out, int out_size, void* d_ws, size_t ws_size,
                              hipStream_t stream) {
    const float* x      = (const float*)d_in[0];
    const float* sinp   = (const float*)d_in[1];
    const float* cosp   = (const float*)d_in[2];
    const float* qkv_w  = (const float*)d_in[3];
    const float* proj_w = (const float*)d_in[4];
    const float* proj_b = (const float*)d_in[5];
    float* out = (float*)d_out;

    char* ws = (char*)d_ws;
    bf16* xb    = (bf16*)(ws);
    bf16* wqkv  = (bf16*)(ws + 8388608);
    bf16* wproj = (bf16*)(ws + 8388608 + 6291456);
    bf16* qkvb  = (bf16*)(ws + 16777216);
    bf16* attno = (bf16*)(ws + 16777216 + 25165824);

    cvt_bf16_kernel<<<4096, 256, 0, stream>>>(x, xb, 4194304);
    cvt_bf16_kernel<<<3072, 256, 0, stream>>>(qkv_w, wqkv, 3145728);
    cvt_bf16_kernel<<<1024, 256, 0, stream>>>(proj_w, wproj, 1048576);

    gemm_bt_kernel<1, 0><<<32 * 24, 256, 0, stream>>>(xb, wqkv, nullptr, qkvb,
                                                      4096, 3072, 1024, 24);
    rope_kernel<<<(ROPE_N + 255) / 256, 256, 0, stream>>>(qkvb, sinp, cosp);
    // attention: 32 (b,h) x 16 q-tiles of 128 rows
    attn_kernel<<<512, 256, 0, stream>>>(qkvb, attno);
    gemm_bt_kernel<0, 1><<<32 * 8, 256, 0, stream>>>(attno, wproj, proj_b, out,
                                                     4096, 1024, 1024, 8);
}

// Round 5
// 158.978 us; speedup vs baseline: 1.5699x; 1.2871x over previous
//
#include <hip/hip_runtime.h>
#include <hip/hip_bf16.h>
#include <stdint.h>

typedef __hip_bfloat16 bf16;
typedef __attribute__((ext_vector_type(8))) short short8;
typedef __attribute__((ext_vector_type(4))) float floatx4;

#define DEVI static __device__ __forceinline__

typedef __attribute__((address_space(1))) const uint32_t gu32;
typedef __attribute__((address_space(3))) uint32_t lu32;

DEVI void gld_lds16(const void* g, void* l) {
    __builtin_amdgcn_global_load_lds((gu32*)g, (lu32*)l, 16, 0, 0);
}

DEVI unsigned short bf2us(bf16 h) { union { bf16 h; unsigned short u; } t; t.h = h; return t.u; }

// RoPE work item count: b(2) * n1(2047) * {q,k}(2) * h(16) * j(32)
#define ROPE_N (2 * 2047 * 2 * 16 * 32)

// ---------------- fp32 -> bf16 convert ----------------
__global__ void cvt_bf16_kernel(const float* __restrict__ src, bf16* __restrict__ dst, int n) {
    int i = (blockIdx.x * 256 + threadIdx.x) * 4;
    if (i >= n) return;
    float4 v = *(const float4*)(src + i);
    union { bf16 h[4]; uint2 u; } o;
    o.h[0] = __float2bfloat16(v.x);
    o.h[1] = __float2bfloat16(v.y);
    o.h[2] = __float2bfloat16(v.z);
    o.h[3] = __float2bfloat16(v.w);
    *(uint2*)(dst + i) = o.u;
}

// ---------------- m97-style bf16 GEMM:  C[M][N] = A[M][K] * Bt[N][K]^T ----------------
// SCALE_Q: multiply cols < 1024 by 0.125 (folds the attention softmax scale into Q).
template<int OUT_BF16, int ADD_BIAS, int SCALE_Q>
__global__ __launch_bounds__(256, 2) void gemm_bt_kernel(
    const bf16* __restrict__ A, const bf16* __restrict__ Bt,
    const float* __restrict__ bias, void* __restrict__ Cout,
    int M, int N, int K, int nbn)
{
    constexpr int BK = 32;
    __shared__ __align__(16) bf16 As[128 * BK];
    __shared__ __align__(16) bf16 Bs[128 * BK];
    const int bm = blockIdx.x / nbn;
    const int bn = blockIdx.x % nbn;
    const int lane = threadIdx.x & 63;
    const int wave = threadIdx.x >> 6;
    const int wm = (wave >> 1) << 6;
    const int wn = (wave & 1) << 6;

    const int srow0 = wave * 16 + (lane >> 2);
    const int srow1 = srow0 + 64;
    const int skc = (lane & 3) * 8;
    const bf16* Ap0 = A + (size_t)(bm * 128 + srow0) * K + skc;
    const bf16* Ap1 = A + (size_t)(bm * 128 + srow1) * K + skc;
    const bf16* Bp0 = Bt + (size_t)(bn * 128 + srow0) * K + skc;
    const bf16* Bp1 = Bt + (size_t)(bn * 128 + srow1) * K + skc;
    bf16* As0 = &As[wave * 512];
    bf16* As1 = &As[wave * 512 + 2048];
    bf16* Bs0 = &Bs[wave * 512];
    bf16* Bs1 = &Bs[wave * 512 + 2048];

    const int frow = lane & 15;
    const int fk   = (lane >> 4) * 8;

    floatx4 acc[4][4] = {};

    for (int kt = 0; kt < K; kt += BK) {
        gld_lds16(Ap0 + kt, As0);
        gld_lds16(Ap1 + kt, As1);
        gld_lds16(Bp0 + kt, Bs0);
        gld_lds16(Bp1 + kt, Bs1);
        __syncthreads();
        short8 af[4], bfv[4];
#pragma unroll
        for (int m = 0; m < 4; ++m) af[m] = *(const short8*)&As[(wm + m * 16 + frow) * BK + fk];
#pragma unroll
        for (int n = 0; n < 4; ++n) bfv[n] = *(const short8*)&Bs[(wn + n * 16 + frow) * BK + fk];
#pragma unroll
        for (int m = 0; m < 4; ++m)
#pragma unroll
            for (int n = 0; n < 4; ++n)
                acc[m][n] = __builtin_amdgcn_mfma_f32_16x16x32_bf16(af[m], bfv[n], acc[m][n], 0, 0, 0);
        __syncthreads();
    }

    const int rbase = bm * 128 + wm + (lane >> 4) * 4;
    const int cbase = bn * 128 + wn + (lane & 15);
#pragma unroll
    for (int m = 0; m < 4; ++m)
#pragma unroll
        for (int n = 0; n < 4; ++n) {
            const int col = cbase + n * 16;
            float bv = ADD_BIAS ? bias[col] : 0.f;
            const float qs = (SCALE_Q && col < 1024) ? 0.125f : 1.0f;
#pragma unroll
            for (int r = 0; r < 4; ++r) {
                const size_t idx = (size_t)(rbase + m * 16 + r) * N + col;
                float v = acc[m][n][r] * qs + bv;
                if (OUT_BF16) ((bf16*)Cout)[idx] = __float2bfloat16(v);
                else          ((float*)Cout)[idx] = v;
            }
        }
}

// ---------------- RoPE in-place on q,k slices of qkv [4096][3072] ----------------
__global__ void rope_kernel(bf16* __restrict__ qkv, const float* __restrict__ sinp,
                            const float* __restrict__ cosp) {
    int idx = blockIdx.x * 256 + threadIdx.x;
    if (idx >= ROPE_N) return;
    const int j = idx & 31;
    int t = idx >> 5;
    const int h = t & 15; t >>= 4;
    const int w = t & 1;  t >>= 1;
    const int n1 = t % 2047;
    const int b  = t / 2047;
    const size_t off = (size_t)(b * 2048 + n1 + 1) * 3072 + w * 1024 + h * 64 + j;
    const float x1 = __bfloat162float(qkv[off]);
    const float x2 = __bfloat162float(qkv[off + 32]);
    const int sc = n1 * 64 + j;
    const float c1 = cosp[sc], s1 = sinp[sc];
    const float c2 = cosp[sc + 32], s2 = sinp[sc + 32];
    qkv[off]      = __float2bfloat16(x1 * c1 - x2 * s1);
    qkv[off + 32] = __float2bfloat16(x2 * c2 + x1 * s2);
}

// ---------------- flash attention v3: swapped QK^T, register-resident softmax/P ----
// 4 waves/block, wave = 32 q-rows (2 strips of 16), block = 128 q-rows, KVBLK=64.
// S^T = mfma(K,Q): lane holds 16 S-values for q = lane&15, k = 16kt + 4g + i (g=lane>>4).
// k' relabeling k' = 8g + 4(kt&1) + i + 32(kt>>1) makes lane's P exactly its PV A-frag
// (no P LDS). V staged transposed in k'-order. Double-buffered K/V, 1 barrier/tile.
__global__ __launch_bounds__(256, 2) void attn_kernel(const bf16* __restrict__ qkv,
                                                      bf16* __restrict__ O) {
    constexpr int LDV = 72;
    __shared__ __align__(16) bf16 Ks[2][64 * 64];   // 16 KiB, source-swizzled chunks
    __shared__ __align__(16) bf16 Vt[2][64 * LDV];  // 18 KiB, [d][k']

    const int bid = blockIdx.x;
    const int bh = bid & 31;        // same (b,h) -> same XCD -> K/V L2-resident
    const int qt = bid >> 5;
    const int b = bh >> 4;
    const int h = bh & 15;
    const int lane = threadIdx.x & 63;
    const int wave = threadIdx.x >> 6;
    const int t = threadIdx.x;

    const bf16* qb = qkv + (size_t)b * 2048 * 3072 + h * 64;
    const bf16* kb = qb + 1024;
    const bf16* vb = qb + 2048;

    const int frow = lane & 15;
    const int ks   = lane >> 4;
    const int fk   = ks * 8;
    const int q0   = qt * 128 + wave * 32;

    // Q (pre-scaled by 0.125 in the qkv GEMM): B-frags, 2 strips x 2 d-halves
    short8 qf[2][2];
#pragma unroll
    for (int s = 0; s < 2; ++s) {
        const bf16* qr = qb + (size_t)(q0 + s * 16 + frow) * 3072;
        qf[s][0] = *(const short8*)(qr + fk);
        qf[s][1] = *(const short8*)(qr + 32 + fk);
    }

    // K staging: source-swizzled global_load_lds (chunk ^= row&7), linear LDS dest
    const int krow0 = wave * 8 + (lane >> 3);
    const int kchunk = ((lane & 7) ^ (lane >> 3)) * 8;
    const bf16* Kp0 = kb + (size_t)krow0 * 3072 + kchunk;
    const bf16* Kp1 = kb + (size_t)(krow0 + 32) * 3072 + kchunk;
    const int ksLds0 = wave * 512;
    const int ksLds1 = (wave + 4) * 512;

    // V staging: thread (vkt = t>>6, vg = (t>>4)&3, cb = t&15) loads V rows
    // 16*vkt + 4*vg + i (i=0..3), 4 cols at cb*4; writes b64 to Vt[d][k'base + i].
    const int vkt = t >> 6;
    const int vg  = (t >> 4) & 3;
    const int cb  = t & 15;
    const int vrow = vkt * 16 + vg * 4;
    const int vkp  = vg * 8 + (vkt & 1) * 4 + (vkt >> 1) * 32;
    const bf16* Vp = vb + (size_t)vrow * 3072 + cb * 4;

    floatx4 acc[2][4] = {};                // [strip][d-tile]: row q=4g+i, col d=frow+16dt
    float mrow[2] = {-1e30f, -1e30f};      // softmax state for q = lane&15
    float lrow[2] = {0.f, 0.f};

    union VU { ushort4 v; unsigned short e[4]; };
    VU vv[4];

    auto loadV = [&](int k0) {
#pragma unroll
        for (int i = 0; i < 4; ++i)
            vv[i].v = *(const ushort4*)(Vp + (size_t)(k0 + i) * 3072);
    };
    auto writeV = [&](int buf) {
#pragma unroll
        for (int j = 0; j < 4; ++j) {
            union { unsigned short u[4]; unsigned long long ll; } pk;
#pragma unroll
            for (int i = 0; i < 4; ++i) pk.u[i] = vv[i].e[j];
            *(unsigned long long*)&Vt[buf][(cb * 4 + j) * LDV + vkp] = pk.ll;
        }
    };
    auto stageK = [&](int k0, int buf) {
        gld_lds16(Kp0 + (size_t)k0 * 3072, &Ks[buf][ksLds0]);
        gld_lds16(Kp1 + (size_t)k0 * 3072, &Ks[buf][ksLds1]);
    };

    // prologue: tile 0 into buffer 0
    loadV(0);
    stageK(0, 0);
    writeV(0);
    __syncthreads();

    for (int tt = 0; tt < 32; ++tt) {
        const int cur = tt & 1;
        if (tt < 31) {                      // issue next tile early (T14)
            loadV((tt + 1) * 64);
            stageK((tt + 1) * 64, cur ^ 1);
        }

        // K A-frags (swizzled read) and V B-frags — shared by both strips
        short8 kf0[4], kf1[4];
#pragma unroll
        for (int kt = 0; kt < 4; ++kt) {
            const int row = kt * 16 + frow;
            kf0[kt] = *(const short8*)&Ks[cur][row * 64 + ((ks ^ (row & 7)) * 8)];
            kf1[kt] = *(const short8*)&Ks[cur][row * 64 + (((ks + 4) ^ (row & 7)) * 8)];
        }
        short8 vf0[4], vf1[4];
#pragma unroll
        for (int dt = 0; dt < 4; ++dt) {
            const int d = dt * 16 + frow;
            vf0[dt] = *(const short8*)&Vt[cur][d * LDV + fk];
            vf1[dt] = *(const short8*)&Vt[cur][d * LDV + 32 + fk];
        }

#pragma unroll
        for (int s = 0; s < 2; ++s) {
            // S^T = K * Q^T : lane -> q = lane&15, k = 16kt + 4g + i
            floatx4 sv[4];
#pragma unroll
            for (int kt = 0; kt < 4; ++kt) {
                floatx4 z = {};
                z = __builtin_amdgcn_mfma_f32_16x16x32_bf16(kf0[kt], qf[s][0], z, 0, 0, 0);
                z = __builtin_amdgcn_mfma_f32_16x16x32_bf16(kf1[kt], qf[s][1], z, 0, 0, 0);
                sv[kt] = z;
            }
            // online softmax for q = lane&15 (16 local values + 2 shuffles)
            float mx = sv[0][0];
#pragma unroll
            for (int kt = 0; kt < 4; ++kt)
#pragma unroll
                for (int i = 0; i < 4; ++i) mx = fmaxf(mx, sv[kt][i]);
            mx = fmaxf(mx, __shfl_xor(mx, 16));
            mx = fmaxf(mx, __shfl_xor(mx, 32));
            const float mnew = fmaxf(mrow[s], mx);
            const float corr = __expf(mrow[s] - mnew);
            mrow[s] = mnew;

            // P in-register: pa0 <- kt 0..1, pa1 <- kt 2..3 (j = 4*(kt&1)+i)
            short8 pa0, pa1;
            float rs = 0.f;
#pragma unroll
            for (int kt = 0; kt < 4; ++kt)
#pragma unroll
                for (int i = 0; i < 4; ++i) {
                    const bf16 pb = __float2bfloat16(__expf(sv[kt][i] - mnew));
                    rs += __bfloat162float(pb);   // denom from rounded values PV uses
                    const short pu = (short)bf2us(pb);
                    if (kt < 2) pa0[kt * 4 + i] = pu;
                    else        pa1[(kt - 2) * 4 + i] = pu;
                }
            rs += __shfl_xor(rs, 16);
            rs += __shfl_xor(rs, 32);
            lrow[s] = lrow[s] * corr + rs;

            // redistribute corr into PV-accumulator lane space (row q = 4g+i)
            floatx4 cvec;
#pragma unroll
            for (int i = 0; i < 4; ++i) cvec[i] = __shfl(corr, (lane >> 4) * 4 + i);
#pragma unroll
            for (int dt = 0; dt < 4; ++dt) {
                acc[s][dt] *= cvec;
                acc[s][dt] = __builtin_amdgcn_mfma_f32_16x16x32_bf16(pa0, vf0[dt], acc[s][dt], 0, 0, 0);
                acc[s][dt] = __builtin_amdgcn_mfma_f32_16x16x32_bf16(pa1, vf1[dt], acc[s][dt], 0, 0, 0);
            }
        }

        if (tt < 31) writeV(cur ^ 1);   // ds-write next tile's V (vmcnt wait here)
        __syncthreads();                 // single barrier per tile
    }

    // epilogue: normalize (redistribute 1/l into accumulator lane space) and store
#pragma unroll
    for (int s = 0; s < 2; ++s) {
        const float inv = 1.0f / lrow[s];
        floatx4 li;
#pragma unroll
        for (int i = 0; i < 4; ++i) li[i] = __shfl(inv, (lane >> 4) * 4 + i);
        const int nrow = q0 + s * 16 + (lane >> 4) * 4;
#pragma unroll
        for (int i = 0; i < 4; ++i) {
            const size_t base = ((size_t)b * 2048 + nrow + i) * 1024 + h * 64 + frow;
#pragma unroll
            for (int dt = 0; dt < 4; ++dt)
                O[base + dt * 16] = __float2bfloat16(acc[s][dt][i] * li[i]);
        }
    }
}

extern "C" void kernel_launch(void* const* d_in, const int* in_sizes, int n_in,
                              void* d_out, int out_size, void* d_ws, size_t ws_size,
                              hipStream_t stream) {
    const float* x      = (const float*)d_in[0];
    const float* sinp   = (const float*)d_in[1];
    const float* cosp   = (const float*)d_in[2];
    const float* qkv_w  = (const float*)d_in[3];
    const float* proj_w = (const float*)d_in[4];
    const float* proj_b = (const float*)d_in[5];
    float* out = (float*)d_out;

    char* ws = (char*)d_ws;
    bf16* xb    = (bf16*)(ws);
    bf16* wqkv  = (bf16*)(ws + 8388608);
    bf16* wproj = (bf16*)(ws + 8388608 + 6291456);
    bf16* qkvb  = (bf16*)(ws + 16777216);
    bf16* attno = (bf16*)(ws + 16777216 + 25165824);

    cvt_bf16_kernel<<<4096, 256, 0, stream>>>(x, xb, 4194304);
    cvt_bf16_kernel<<<3072, 256, 0, stream>>>(qkv_w, wqkv, 3145728);
    cvt_bf16_kernel<<<1024, 256, 0, stream>>>(proj_w, wproj, 1048576);

    // qkv = x @ qkv_w^T (q-part pre-scaled by 0.125)
    gemm_bt_kernel<1, 0, 1><<<32 * 24, 256, 0, stream>>>(xb, wqkv, nullptr, qkvb,
                                                         4096, 3072, 1024, 24);
    rope_kernel<<<(ROPE_N + 255) / 256, 256, 0, stream>>>(qkvb, sinp, cosp);
    attn_kernel<<<512, 256, 0, stream>>>(qkvb, attno);
    gemm_bt_kernel<0, 1, 0><<<32 * 8, 256, 0, stream>>>(attno, wproj, proj_b, out,
                                                        4096, 1024, 1024, 8);
}